// Round 5
// baseline (85.477 us; speedup 1.0000x reference)
//
#include <hip/hip_runtime.h>

#define GROUPS 64
#define DIMS 8
#define ACCW 10      // 8 sums + ssq + count
#define LSTRIDE 11   // LDS int stride (break pow2 bank pattern)
#define BPI 128      // blocks per image
#define BLK 512      // 8 waves/block (R3 proven config)
#define WAVES 8
#define NIMG 8
#define RREP 8       // gacc replicas: spread the flush-atomic storm over 8x lines
#define SCALE 262144.0f          // 2^18
#define INV_SCALE (1.0f / 262144.0f)

__global__ __launch_bounds__(BLK, 8) void k_accum(const float* __restrict__ pred,
                                                  const int* __restrict__ gt,
                                                  unsigned long long* __restrict__ gacc,
                                                  unsigned long long* __restrict__ ticket,
                                                  float* __restrict__ out,
                                                  int N) {
    __shared__ int acc[WAVES][GROUPS * LSTRIDE];   // 22528 B; finisher reuses as smf
    __shared__ float lossArr[NIMG];
    __shared__ int isLast;

    const int tid = threadIdx.x;
    const int wave = tid >> 6;
    const int b = blockIdx.y;
    for (int i = tid; i < WAVES * GROUPS * LSTRIDE; i += BLK) ((int*)acc)[i] = 0;
    __syncthreads();

    const float4* pb = (const float4*)(pred + (size_t)b * N * DIMS);
    const int* gb = gt + (size_t)b * N;
    for (int idx = blockIdx.x * BLK + tid; idx < N; idx += BPI * BLK) {
        int g = gb[idx];
        float4 p0 = pb[2 * idx];
        float4 p1 = pb[2 * idx + 1];
        int* a = &acc[wave][g * LSTRIDE];
        atomicAdd(a + 0, __float2int_rn(p0.x * SCALE));
        atomicAdd(a + 1, __float2int_rn(p0.y * SCALE));
        atomicAdd(a + 2, __float2int_rn(p0.z * SCALE));
        atomicAdd(a + 3, __float2int_rn(p0.w * SCALE));
        atomicAdd(a + 4, __float2int_rn(p1.x * SCALE));
        atomicAdd(a + 5, __float2int_rn(p1.y * SCALE));
        atomicAdd(a + 6, __float2int_rn(p1.z * SCALE));
        atomicAdd(a + 7, __float2int_rn(p1.w * SCALE));
        float ssq = p0.x*p0.x + p0.y*p0.y + p0.z*p0.z + p0.w*p0.w
                  + p1.x*p1.x + p1.y*p1.y + p1.z*p1.z + p1.w*p1.w;
        atomicAdd(a + 8, __float2int_rn(ssq * SCALE));
        atomicAdd(a + 9, 1);
    }
    __syncthreads();

    // Flush block partials. ONLY change vs R3: target replica (blockIdx.x & 7)
    // so the simultaneous end-of-kernel atomic storm is spread over 8x the
    // cache lines (per-line serial chain 2048 -> 256 RMWs).
    {
        const int rep = blockIdx.x & (RREP - 1);
        unsigned long long* gr = gacc + (size_t)rep * NIMG * GROUPS * ACCW;
        for (int i = tid; i < GROUPS * ACCW; i += BLK) {
            int g = i / ACCW, k = i % ACCW;
            long long v = 0;
            for (int c = 0; c < WAVES; ++c) v += (long long)acc[c][g * LSTRIDE + k];
            atomicAdd(&gr[(b * GROUPS + g) * ACCW + k], (unsigned long long)v);
        }
    }

    // __syncthreads drains vmcnt(0) per wave, so this block's device-scope gacc
    // atomics are complete at the coherent point before the ticket RMW below.
    // RELAXED scope-agent RMW: no L2 writeback/invalidate (the acq_rel flush
    // storm was the round-1/2 regression).
    __syncthreads();
    if (tid == 0) {
        unsigned long long t = __hip_atomic_fetch_add(ticket, 1ull, __ATOMIC_RELAXED,
                                                      __HIP_MEMORY_SCOPE_AGENT);
        isLast = (t == (unsigned long long)(BPI * NIMG) - 1ull) ? 1 : 0;
    }
    __syncthreads();
    if (!isLast) return;

    // ---------- finisher: runs once in the last block ----------
    float (*smf)[DIMS + 1] = (float (*)[DIMS + 1])(&acc[0][0]);  // [NIMG*GROUPS][9]
    const int ib = tid >> 6;    // one wave per image (8 waves, 8 images)
    const int g = tid & 63;

    long long ga[ACCW];
    for (int k = 0; k < ACCW; ++k) ga[k] = 0;
    for (int r = 0; r < RREP; ++r) {
        const unsigned long long* gp = gacc + ((size_t)r * NIMG + ib) * GROUPS * ACCW
                                            + (size_t)g * ACCW;
        for (int k = 0; k < ACCW; ++k)
            ga[k] += (long long)__hip_atomic_load(gp + k, __ATOMIC_RELAXED,
                                                  __HIP_MEMORY_SCOPE_AGENT);
    }
    float c = (float)ga[9];
    float ssq = (float)ga[8] * INV_SCALE;
    float safe = fmaxf(c, 1.f);
    float m[DIMS];
    float msq = 0.f;
    for (int d = 0; d < DIMS; ++d) {
        m[d] = ((float)ga[d] * INV_SCALE) / safe;
        smf[ib * GROUPS + g][d] = m[d];
        msq += m[d] * m[d];
    }
    bool present = c > 0.f;
    smf[ib * GROUPS + g][DIMS] = present ? 1.f : 0.f;

    float sumsq = ssq - c * msq;
    float pull_g = present ? sumsq / (safe * (float)DIMS) : 0.f;

    unsigned long long mask = __ballot(present);
    float num = (float)__popcll(mask);

    float pull = pull_g;
    for (int off = 32; off; off >>= 1) pull += __shfl_xor(pull, off);

    __syncthreads();   // means table complete for all 8 images

    float pg = 0.f;
    if (present) {
        for (int j = 0; j < GROUPS; ++j) {
            const float* rj = smf[ib * GROUPS + j];
            float pm = rj[DIMS];
            float d2 = 0.f;
            for (int d = 0; d < DIMS; ++d) {
                float t2 = m[d] - rj[d];
                d2 += t2 * t2;
            }
            pg += pm * expf(-d2);
        }
    }
    for (int off = 32; off; off >>= 1) pg += __shfl_xor(pg, off);

    if (g == 0) {
        float push = (pg - num) / ((num - 1.f) * num + 1e-6f) * 0.5f;
        lossArr[ib] = push + pull / (num + 1e-6f);
    }
    __syncthreads();
    if (tid == 0) {
        float s = 0.f;
        for (int i = 0; i < NIMG; ++i) s += lossArr[i];
        out[0] = s * (1.f / (float)NIMG);
    }
}

extern "C" void kernel_launch(void* const* d_in, const int* in_sizes, int n_in,
                              void* d_out, int out_size, void* d_ws, size_t ws_size,
                              hipStream_t stream) {
    const float* pred = (const float*)d_in[0];
    const int* gt = (const int*)d_in[1];
    const int N = in_sizes[1] / NIMG;   // 500000

    unsigned long long* gacc = (unsigned long long*)d_ws;      // [RREP][NIMG][GROUPS][ACCW]
    unsigned long long* ticket = gacc + RREP * NIMG * GROUPS * ACCW;

    hipMemsetAsync(d_ws, 0, (RREP * NIMG * GROUPS * ACCW + 1) * sizeof(unsigned long long),
                   stream);

    dim3 grid(BPI, NIMG);
    k_accum<<<grid, BLK, 0, stream>>>(pred, gt, gacc, ticket, (float*)d_out, N);
}

// Round 6
// 44.673 us; speedup vs baseline: 1.9134x; 1.9134x over previous
//
#include <hip/hip_runtime.h>

#define GROUPS 64
#define DIMS 8
#define ACCW 10      // 8 sums + ssq + count
#define LSTRIDE 11   // LDS int stride (break pow2 bank pattern)
#define BPI 128      // blocks per image
#define BLK 256
#define NIMG 8
#define SCALE 262144.0f          // 2^18
#define INV_SCALE (1.0f / 262144.0f)

__global__ void k_zero(unsigned long long* p, int n) {
    int i = blockIdx.x * blockDim.x + threadIdx.x;
    if (i < n) p[i] = 0ull;
}

__global__ __launch_bounds__(BLK) void k_accum(const float* __restrict__ pred,
                                               const int* __restrict__ gt,
                                               unsigned long long* __restrict__ gacc,
                                               int N) {
    __shared__ int acc[4][GROUPS * LSTRIDE];
    const int tid = threadIdx.x;
    const int wave = tid >> 6;
    const int b = blockIdx.y;
    for (int i = tid; i < 4 * GROUPS * LSTRIDE; i += BLK) ((int*)acc)[i] = 0;
    __syncthreads();

    const float4* pb = (const float4*)(pred + (size_t)b * N * DIMS);
    const int* gb = gt + (size_t)b * N;
    int* const accw = &acc[wave][0];

    // Depth-2 software pipeline: iteration i's gt/pred loads are issued two
    // atomic-clusters ahead of use, hiding the ~200-900 cyc load latency that
    // the warm-run profile (77 us at 21 MB HBM traffic, VALUBusy 4.7%) showed
    // to be the critical path. Arithmetic is bit-identical to the R0 baseline.
    const int STEP = BPI * BLK;
    int idx0 = blockIdx.x * BLK + tid;
    bool h0 = idx0 < N;
    int g0 = 0; float4 a0, a1;
    if (h0) { g0 = gb[idx0]; a0 = pb[2 * idx0]; a1 = pb[2 * idx0 + 1]; }

    int idx1 = idx0 + STEP;
    bool h1 = idx1 < N;
    int g1 = 0; float4 b0, b1;
    if (h1) { g1 = gb[idx1]; b0 = pb[2 * idx1]; b1 = pb[2 * idx1 + 1]; }

    int idxn = idx1 + STEP;
    while (h0) {
        // prefetch iter i+2
        bool hn = idxn < N;
        int gn = 0; float4 c0, c1;
        if (hn) { gn = gb[idxn]; c0 = pb[2 * idxn]; c1 = pb[2 * idxn + 1]; }

        // process iter i
        int* a = accw + g0 * LSTRIDE;
        atomicAdd(a + 0, __float2int_rn(a0.x * SCALE));
        atomicAdd(a + 1, __float2int_rn(a0.y * SCALE));
        atomicAdd(a + 2, __float2int_rn(a0.z * SCALE));
        atomicAdd(a + 3, __float2int_rn(a0.w * SCALE));
        atomicAdd(a + 4, __float2int_rn(a1.x * SCALE));
        atomicAdd(a + 5, __float2int_rn(a1.y * SCALE));
        atomicAdd(a + 6, __float2int_rn(a1.z * SCALE));
        atomicAdd(a + 7, __float2int_rn(a1.w * SCALE));
        float ssq = a0.x*a0.x + a0.y*a0.y + a0.z*a0.z + a0.w*a0.w
                  + a1.x*a1.x + a1.y*a1.y + a1.z*a1.z + a1.w*a1.w;
        atomicAdd(a + 8, __float2int_rn(ssq * SCALE));
        atomicAdd(a + 9, 1);

        // rotate
        g0 = g1; a0 = b0; a1 = b1; h0 = h1;
        g1 = gn; b0 = c0; b1 = c1; h1 = hn;
        idxn += STEP;
    }
    __syncthreads();

    for (int i = tid; i < GROUPS * ACCW; i += BLK) {
        int g = i / ACCW, k = i % ACCW;
        long long v = (long long)acc[0][g * LSTRIDE + k]
                    + (long long)acc[1][g * LSTRIDE + k]
                    + (long long)acc[2][g * LSTRIDE + k]
                    + (long long)acc[3][g * LSTRIDE + k];
        atomicAdd(&gacc[(b * GROUPS + g) * ACCW + k], (unsigned long long)v);
    }
}

__global__ __launch_bounds__(512) void k_final(const unsigned long long* __restrict__ gacc,
                                               float* __restrict__ out) {
    __shared__ float sm[NIMG][GROUPS][DIMS + 1];
    __shared__ float lossArr[NIMG];
    const int tid = threadIdx.x;
    const int b = tid >> 6;     // image (wave)
    const int g = tid & 63;     // group (lane)

    const unsigned long long* ga = gacc + (b * GROUPS + g) * ACCW;
    float c = (float)(long long)ga[9];
    float ssq = (float)(long long)ga[8] * INV_SCALE;
    float safe = fmaxf(c, 1.f);
    float m[DIMS];
    float msq = 0.f;
    for (int d = 0; d < DIMS; ++d) {
        m[d] = ((float)(long long)ga[d] * INV_SCALE) / safe;
        sm[b][g][d] = m[d];
        msq += m[d] * m[d];
    }
    bool present = c > 0.f;
    sm[b][g][DIMS] = present ? 1.f : 0.f;

    float sumsq = ssq - c * msq;
    float pull_g = present ? sumsq / (safe * (float)DIMS) : 0.f;

    unsigned long long mask = __ballot(present);
    float num = (float)__popcll(mask);

    float pull = pull_g;
    for (int off = 32; off; off >>= 1) pull += __shfl_xor(pull, off);

    __syncthreads();

    float pg = 0.f;
    if (present) {
        for (int j = 0; j < GROUPS; ++j) {
            float pm = sm[b][j][DIMS];
            float d2 = 0.f;
            for (int d = 0; d < DIMS; ++d) {
                float t = m[d] - sm[b][j][d];
                d2 += t * t;
            }
            pg += pm * expf(-d2);
        }
    }
    for (int off = 32; off; off >>= 1) pg += __shfl_xor(pg, off);

    if (g == 0) {
        float push = (pg - num) / ((num - 1.f) * num + 1e-6f) * 0.5f;
        float pl = pull / (num + 1e-6f);
        lossArr[b] = push + pl;
    }
    __syncthreads();

    if (tid == 0) {
        float s = 0.f;
        for (int i = 0; i < NIMG; ++i) s += lossArr[i];
        out[0] = s * (1.f / (float)NIMG);
    }
}

extern "C" void kernel_launch(void* const* d_in, const int* in_sizes, int n_in,
                              void* d_out, int out_size, void* d_ws, size_t ws_size,
                              hipStream_t stream) {
    const float* pred = (const float*)d_in[0];
    const int* gt = (const int*)d_in[1];
    const int N = in_sizes[1] / NIMG;   // 500000

    unsigned long long* gacc = (unsigned long long*)d_ws;  // [NIMG][GROUPS][ACCW]
    const int accN = NIMG * GROUPS * ACCW;

    k_zero<<<(accN + 255) / 256, 256, 0, stream>>>(gacc, accN);
    dim3 grid(BPI, NIMG);
    k_accum<<<grid, BLK, 0, stream>>>(pred, gt, gacc, N);
    k_final<<<1, 512, 0, stream>>>(gacc, (float*)d_out);
}